// Round 1
// baseline (431.787 us; speedup 1.0000x reference)
//
#include <hip/hip_runtime.h>
#include <hip/hip_bf16.h>
#include <math.h>

// ---------------- problem constants ----------------
#define B_SZ   2
#define L_SZ   2048
#define DM     1024          // d_model
#define DI     2048          // d_inner
#define DS     16            // d_state
#define M_SZ   (B_SZ * L_SZ) // 4096 rows
#define N_XZ   (2 * DI)      // 4096
#define LDF    20            // uints per LDS row (32 bf16 + 8 pad) -- r8-proven

typedef short bf16x8 __attribute__((ext_vector_type(8)));
typedef float f32x4  __attribute__((ext_vector_type(4)));

__device__ __forceinline__ unsigned short rne16(float f) {
  unsigned int u = __builtin_bit_cast(unsigned int, f);
  u += 0x7FFFu + ((u >> 16) & 1u);
  return (unsigned short)(u >> 16);
}
__device__ __forceinline__ float frombf(unsigned short h) {
  unsigned int u = ((unsigned int)h) << 16;
  return __builtin_bit_cast(float, u);
}

// ---------------- x -> (x_hi, x_lo) bf16 split ----------------
__global__ __launch_bounds__(256) void convert_x(
    const float* __restrict__ x, unsigned short* __restrict__ xh,
    unsigned short* __restrict__ xl) {
  int i = (blockIdx.x * 256 + threadIdx.x) * 4;
  float4 v = *(const float4*)(x + i);
  unsigned short h0 = rne16(v.x), h1 = rne16(v.y), h2 = rne16(v.z), h3 = rne16(v.w);
  *(ushort4*)(xh + i) = make_ushort4(h0, h1, h2, h3);
  *(ushort4*)(xl + i) = make_ushort4(rne16(v.x - frombf(h0)), rne16(v.y - frombf(h1)),
                                     rne16(v.z - frombf(h2)), rne16(v.w - frombf(h3)));
}

// ---------------- W (RxC fp32) -> W^T (CxR) bf16 hi (+lo) ----------------
__global__ __launch_bounds__(256) void transpose_w(
    const float* __restrict__ in, int R, int C,
    unsigned short* __restrict__ oh, unsigned short* __restrict__ ol) {
  __shared__ float T[64][65];
  const int tid = threadIdx.x;
  const int c0 = blockIdx.x * 64, r0 = blockIdx.y * 64;
  const int cc = tid & 63, rq = tid >> 6;
  #pragma unroll
  for (int i = 0; i < 16; ++i) {
    int r = rq * 16 + i;
    T[r][cc] = in[(size_t)(r0 + r) * C + c0 + cc];
  }
  __syncthreads();
  #pragma unroll
  for (int i = 0; i < 16; ++i) {
    int c = rq * 16 + i;
    float v = T[cc][c];
    size_t o = (size_t)(c0 + c) * R + r0 + cc;
    unsigned short h = rne16(v);
    oh[o] = h;
    if (ol) ol[o] = rne16(v - frombf(h));
  }
}

// ---------------- bf16 MFMA GEMM (optionally bf16x3), pre-converted inputs ----------------
// EXACT r8-proven body (LDF=20, launch_bounds (256, X3?3:4)); only the epilogue
// output path is parameterized (OUTBF16).
// A: M x K bf16 row-major (hi[, lo]); B: N x K bf16 row-major (pre-transposed).
// X3: D = Ah*Bh + Ah*Bl + Al*Bh (~2^-17 rel err vs fp32).
template<int BN, bool X3, bool OUTBF16>
__global__ __launch_bounds__(256, X3 ? 3 : 4) void gemm_t(
    const unsigned short* __restrict__ Ah, const unsigned short* __restrict__ Al, int lda,
    const unsigned short* __restrict__ Bh, const unsigned short* __restrict__ Bl, int ldb,
    const float* __restrict__ bias, float* __restrict__ Cf,
    unsigned short* __restrict__ Cz, int ldc, int K) {
  constexpr int WN  = BN / 2;      // wave col extent
  constexpr int FJ  = BN / 32;     // col frags per wave
  constexpr int BCH = BN / 64;     // B staging chunks per thread
  __shared__ unsigned int AhS[128 * LDF];
  __shared__ unsigned int BhS[BN * LDF];
  __shared__ unsigned int AlS[X3 ? 128 * LDF : 4];
  __shared__ unsigned int BlS[X3 ? BN * LDF : 4];
  const int tid  = threadIdx.x;
  const int lane = tid & 63, wave = tid >> 6;
  const int wr = wave >> 1, wc = wave & 1;
  const int lm = lane & 15, lq = lane >> 4;
  const int row0 = blockIdx.y * 128, col0 = blockIdx.x * BN;

  f32x4 acc[4][FJ];
  #pragma unroll
  for (int i = 0; i < 4; ++i)
    #pragma unroll
    for (int j = 0; j < FJ; ++j) acc[i][j] = (f32x4){0.f, 0.f, 0.f, 0.f};

  for (int k0 = 0; k0 < K; k0 += 32) {
    __syncthreads();
    // A tiles: 128 rows x 32 k, uint4 (8 bf16) per chunk
    #pragma unroll
    for (int i = 0; i < 2; ++i) {
      int idx = tid + i * 256, r = idx >> 2, q = idx & 3;
      size_t go = (size_t)(row0 + r) * lda + k0 + q * 8;
      *(uint4*)&AhS[r * LDF + q * 4] = *(const uint4*)(Ah + go);
      if constexpr (X3)
        *(uint4*)&AlS[r * LDF + q * 4] = *(const uint4*)(Al + go);
    }
    // B tiles: BN rows (n) x 32 k
    #pragma unroll
    for (int i = 0; i < BCH; ++i) {
      int idx = tid + i * 256, r = idx >> 2, q = idx & 3;
      size_t go = (size_t)(col0 + r) * ldb + k0 + q * 8;
      *(uint4*)&BhS[r * LDF + q * 4] = *(const uint4*)(Bh + go);
      if constexpr (X3)
        *(uint4*)&BlS[r * LDF + q * 4] = *(const uint4*)(Bl + go);
    }
    __syncthreads();
    bf16x8 bh[FJ], bl[FJ];
    #pragma unroll
    for (int j = 0; j < FJ; ++j) {
      bh[j] = *(const bf16x8*)&BhS[(wc * WN + j * 16 + lm) * LDF + lq * 4];
      if constexpr (X3)
        bl[j] = *(const bf16x8*)&BlS[(wc * WN + j * 16 + lm) * LDF + lq * 4];
    }
    #pragma unroll
    for (int i = 0; i < 4; ++i) {
      bf16x8 ah = *(const bf16x8*)&AhS[(wr * 64 + i * 16 + lm) * LDF + lq * 4];
      bf16x8 al;
      if constexpr (X3)
        al = *(const bf16x8*)&AlS[(wr * 64 + i * 16 + lm) * LDF + lq * 4];
      #pragma unroll
      for (int j = 0; j < FJ; ++j) {
        acc[i][j] = __builtin_amdgcn_mfma_f32_16x16x32_bf16(ah, bh[j], acc[i][j], 0, 0, 0);
        if constexpr (X3) {
          acc[i][j] = __builtin_amdgcn_mfma_f32_16x16x32_bf16(ah, bl[j], acc[i][j], 0, 0, 0);
          acc[i][j] = __builtin_amdgcn_mfma_f32_16x16x32_bf16(al, bh[j], acc[i][j], 0, 0, 0);
        }
      }
    }
  }
  // epilogue: C/D layout col=lane&15, row=(lane>>4)*4+reg
  #pragma unroll
  for (int i = 0; i < 4; ++i) {
    #pragma unroll
    for (int j = 0; j < FJ; ++j) {
      int c = col0 + wc * WN + j * 16 + lm;
      float bs = bias[c];
      #pragma unroll
      for (int k = 0; k < 4; ++k) {
        int r = row0 + wr * 64 + i * 16 + lq * 4 + k;
        float v = acc[i][j][k] + bs;
        if constexpr (OUTBF16) Cz[(size_t)r * ldc + c] = rne16(v);
        else                   Cf[(size_t)r * ldc + c] = v;
      }
    }
  }
}

// ---------------- depthwise causal conv (k=4, left pad 3) + SiLU ----------------
__global__ __launch_bounds__(256) void conv_silu_kernel(
    const float* __restrict__ xi, const float* __restrict__ Wc,
    const float* __restrict__ bc, float* __restrict__ xc) {
  int idx = blockIdx.x * blockDim.x + threadIdx.x;   // over M_SZ*DI
  if (idx >= M_SZ * DI) return;
  int d  = idx & (DI - 1);
  int bl = idx >> 11;            // row (b*L + l)
  int l  = bl & (L_SZ - 1);
  float4 w = ((const float4*)Wc)[d];
  const float* base = xi + (size_t)bl * DI + d;
  float s = bc[d] + base[0] * w.w;
  if (l >= 1) s = fmaf(base[-DI],     w.z, s);
  if (l >= 2) s = fmaf(base[-2 * DI], w.y, s);
  if (l >= 3) s = fmaf(base[-3 * DI], w.x, s);
  float sig = 1.f / (1.f + expf(-s));
  xc[idx] = s * sig;
}

// ---------------- skinny GEMM: Bm = xc @ W_B + b_B ; Cm = xc @ W_C + b_C ----------------
__global__ __launch_bounds__(256) void gemm_bc_kernel(
    const float* __restrict__ xc,
    const float* __restrict__ WB, const float* __restrict__ bB,
    const float* __restrict__ WC, const float* __restrict__ bC,
    float* __restrict__ Bm, float* __restrict__ Cm) {
  int t = blockIdx.x * blockDim.x + threadIdx.x;  // M_SZ*32
  int row = t >> 5;
  int cc  = t & 31;
  int s   = cc & 15;
  const float* W = (cc < 16) ? WB : WC;
  const float4* xr4 = (const float4*)(xc + (size_t)row * DI);
  float acc = 0.f;
  #pragma unroll 4
  for (int k4 = 0; k4 < DI / 4; ++k4) {
    float4 xv = xr4[k4];
    int k = k4 * 4;
    acc = fmaf(xv.x, W[(k    ) * DS + s], acc);
    acc = fmaf(xv.y, W[(k + 1) * DS + s], acc);
    acc = fmaf(xv.z, W[(k + 2) * DS + s], acc);
    acc = fmaf(xv.w, W[(k + 3) * DS + s], acc);
  }
  if (cc < 16) Bm[row * DS + s] = acc + bB[s];
  else         Cm[row * DS + s] = acc + bC[s];
}

// ---------------- selective scan ----------------
// v2: 16 channels/block = 4 independent barrier-free waves (4 ch each).
//   * per-row global footprint: xc 64B (full line, was 16B), zb 32B, yg 32B
//     -> kills the 4x FETCH amplification seen in rocprof (202MB -> ~70MB).
//   * s-reduction via DPP row_ror rotate-add within the 16-lane group (VALU pipe)
//     instead of the Ps LDS round-trip (shared per-CU LDS pipe, was 17.4KB/wave).
//   * D*x folded into lane s==0's partial; z kept in registers (lane==row).
//   * raw s_barrier (no waitcnt drain) per chunk only to keep waves line-sharing.
// Validated semantics identical to r6/r8 scan (clip points, gating order).
#define WCH    4     // channels per wave
#define SCH    16    // channels per block (4 waves)
#define CHUNK  64
#define XSTR   66    // Xs2 [ch][l] padded stride
#define WLDSF  (WCH * XSTR + CHUNK * 32 + CHUNK * 4)  // floats per wave = 2568

template<int N> __device__ __forceinline__ float rot16(float x) {
  // DPP row_ror:N -- rotate within the hardware 16-lane row
  return __builtin_bit_cast(float,
      __builtin_amdgcn_update_dpp(0, __builtin_bit_cast(int, x),
                                  0x120 | N, 0xF, 0xF, false));
}

__global__ __launch_bounds__(256) void scan_kernel(
    const float* __restrict__ xc, const unsigned short* __restrict__ zb,
    const float* __restrict__ Bm, const float* __restrict__ Cm,
    const float* __restrict__ A_log, const float* __restrict__ Dv,
    unsigned short* __restrict__ yg) {
  const int b    = blockIdx.y;
  const int tid  = threadIdx.x;
  const int wave = tid >> 6;
  const int lane = tid & 63;
  const int dd   = lane >> 4;      // 0..3 channel within wave
  const int s    = lane & 15;      // state
  const int dw0  = blockIdx.x * SCH + wave * WCH;

  __shared__ float SM[4 * WLDSF];
  float* Xs2 = SM + wave * WLDSF;        // [4][XSTR]  x per channel per l
  float* BCs = Xs2 + WCH * XSTR;         // [l][s][{B,C}] interleaved
  float* yS  = BCs + CHUNK * 32;         // [l][ch] y-sum gather buffer

  float Alog = A_log[(dw0 + dd) * DS + s];
  Alog = fminf(fmaxf(Alog, -10.f), 2.f);
  const float A    = -expf(Alog);
  const float dsel = (s == 0) ? Dv[dw0 + dd] : 0.f;   // D*x contributed once per group
  float h = 0.f;

  const size_t rbase = (size_t)b * L_SZ;

  float4 pX, pB[4], pC[4];
  uint2 pZ;
  {
    size_t row = rbase + lane;
    pX = *(const float4*)(xc + row * DI + dw0);
    pZ = *(const uint2*)(zb + row * DI + dw0);
    #pragma unroll
    for (int i = 0; i < 4; ++i) {
      int idx = lane + i * 64;
      size_t rr = rbase + (idx >> 2);
      pB[i] = *(const float4*)(Bm + rr * DS + (idx & 3) * 4);
      pC[i] = *(const float4*)(Cm + rr * DS + (idx & 3) * 4);
    }
  }

  for (int l0 = 0; l0 < L_SZ; l0 += CHUNK) {
    __builtin_amdgcn_s_barrier();   // temporal alignment only; no LDS sharing
    // stage current chunk (wave-private LDS)
    Xs2[0 * XSTR + lane] = pX.x;
    Xs2[1 * XSTR + lane] = pX.y;
    Xs2[2 * XSTR + lane] = pX.z;
    Xs2[3 * XSTR + lane] = pX.w;
    #pragma unroll
    for (int i = 0; i < 4; ++i) {
      int idx = lane + i * 64;
      float* bb = BCs + idx * 8;
      *(float2*)(bb + 0) = make_float2(pB[i].x, pC[i].x);
      *(float2*)(bb + 2) = make_float2(pB[i].y, pC[i].y);
      *(float2*)(bb + 4) = make_float2(pB[i].z, pC[i].z);
      *(float2*)(bb + 6) = make_float2(pB[i].w, pC[i].w);
    }
    const uint2 zc = pZ;           // z for this chunk, lane == row
    if (l0 + CHUNK < L_SZ) {       // prefetch next chunk
      size_t row = rbase + l0 + CHUNK + lane;
      pX = *(const float4*)(xc + row * DI + dw0);
      pZ = *(const uint2*)(zb + row * DI + dw0);
      #pragma unroll
      for (int i = 0; i < 4; ++i) {
        int idx = lane + i * 64;
        size_t rr = rbase + l0 + CHUNK + (idx >> 2);
        pB[i] = *(const float4*)(Bm + rr * DS + (idx & 3) * 4);
        pC[i] = *(const float4*)(Cm + rr * DS + (idx & 3) * 4);
      }
    }
    float yk[4];
    #pragma unroll
    for (int lq = 0; lq < 4; ++lq) {
      float ysel = 0.f;
      #pragma unroll
      for (int u = 0; u < 16; u += 2) {
        const int l = lq * 16 + u;
        float2 x2  = *(const float2*)&Xs2[dd * XSTR + l];
        float2 bc0 = *(const float2*)&BCs[l * 32 + s * 2];
        float2 bc1 = *(const float2*)&BCs[(l + 1) * 32 + s * 2];
        h = fmaf(h, A, x2.x * bc0.x);
        h = fminf(fmaxf(h, -100.f), 100.f);
        float p0 = fmaf(dsel, x2.x, h * bc0.y);
        h = fmaf(h, A, x2.y * bc1.x);
        h = fminf(fmaxf(h, -100.f), 100.f);
        float p1 = fmaf(dsel, x2.y, h * bc1.y);
        // rotate-add reduce over the 16 states (all lanes end with full sum)
        p0 += rot16<8>(p0); p0 += rot16<4>(p0); p0 += rot16<2>(p0); p0 += rot16<1>(p0);
        p1 += rot16<8>(p1); p1 += rot16<4>(p1); p1 += rot16<2>(p1); p1 += rot16<1>(p1);
        if (s == u)     ysel = p0;   // lane s keeps y for l == lq*16 + s
        if (s == u + 1) ysel = p1;
      }
      yk[lq] = ysel;                 // lq is unroll-constant: stays in registers
    }
    // gather: lane (dd,s) holds y[dd][s+16q]; transpose via 1KB LDS so that
    // lane l can emit ushort4 {y[0..3][l]} in one 8B store.
    #pragma unroll
    for (int q = 0; q < 4; ++q)
      yS[(s + q * 16) * 4 + dd] = yk[q];
    float4 yv = *(const float4*)&yS[lane * 4];
    float zf0 = frombf((unsigned short)(zc.x & 0xFFFF));
    float zf1 = frombf((unsigned short)(zc.x >> 16));
    float zf2 = frombf((unsigned short)(zc.y & 0xFFFF));
    float zf3 = frombf((unsigned short)(zc.y >> 16));
    ushort4 o;
    o.x = rne16(fminf(fmaxf(yv.x, -100.f), 100.f) * (1.f / (1.f + expf(-zf0))));
    o.y = rne16(fminf(fmaxf(yv.y, -100.f), 100.f) * (1.f / (1.f + expf(-zf1))));
    o.z = rne16(fminf(fmaxf(yv.z, -100.f), 100.f) * (1.f / (1.f + expf(-zf2))));
    o.w = rne16(fminf(fmaxf(yv.w, -100.f), 100.f) * (1.f / (1.f + expf(-zf3))));
    *(ushort4*)(yg + (rbase + l0 + lane) * DI + dw0) = o;
  }
}

// ---------------- launch ----------------
// ws layout (bytes), peak 88.6 MB (unchanged):
//   [0,        33554432)  xi fp32 (GEMM1 out, conv in); first 16 MB reused as yg bf16 after conv
//   [33554432, 50331648)  z bf16
//   [50331648, 83886080)  xc fp32 (conv out); BEFORE conv hosts xh/xl/WhT/WlT (8 MB each)
//   [83886080, 84148224)  Bm
//   [84148224, 84410368)  Cm
//   [84410368, 88604672)  WoutT bf16
extern "C" void kernel_launch(void* const* d_in, const int* in_sizes, int n_in,
                              void* d_out, int out_size, void* d_ws, size_t ws_size,
                              hipStream_t stream) {
  const float* x      = (const float*)d_in[0];
  const float* W_in   = (const float*)d_in[1];
  const float* b_in   = (const float*)d_in[2];
  const float* W_conv = (const float*)d_in[3];
  const float* b_conv = (const float*)d_in[4];
  const float* A_log  = (const float*)d_in[5];
  const float* Dv     = (const float*)d_in[6];
  const float* W_B    = (const float*)d_in[7];
  const float* b_B    = (const float*)d_in[8];
  const float* W_C    = (const float*)d_in[9];
  const float* b_C    = (const float*)d_in[10];
  const float* W_out  = (const float*)d_in[11];
  const float* b_out  = (const float*)d_in[12];
  float* out = (float*)d_out;

  char* w = (char*)d_ws;
  float*          xi   = (float*)(w + 0);
  unsigned short* yg   = (unsigned short*)(w + 0);          // reuse after conv
  unsigned short* zb   = (unsigned short*)(w + 33554432);
  float*          xc   = (float*)(w + 50331648);
  unsigned short* xh   = (unsigned short*)(w + 50331648);   // pre-conv phase
  unsigned short* xl   = (unsigned short*)(w + 58720256);
  unsigned short* WhT  = (unsigned short*)(w + 67108864);
  unsigned short* WlT  = (unsigned short*)(w + 75497472);
  float*          Bm   = (float*)(w + 83886080);
  float*          Cm   = (float*)(w + 84148224);
  unsigned short* WoT  = (unsigned short*)(w + 84410368);

  // 0a) x -> xh/xl
  convert_x<<<M_SZ * DM / 1024, 256, 0, stream>>>(x, xh, xl);
  // 0b) W_in (DM x N_XZ) -> WhT/WlT (N_XZ x DM)
  transpose_w<<<dim3(N_XZ / 64, DM / 64), 256, 0, stream>>>(W_in, DM, N_XZ, WhT, WlT);
  // 0c) W_out (DI x DM) -> WoT (DM x DI), hi only (post-scan path)
  transpose_w<<<dim3(DM / 64, DI / 64), 256, 0, stream>>>(W_out, DI, DM, WoT, nullptr);

  // 1a) xi = x @ W_in[:, :DI] + b_in[:DI]  -- bf16x3 (scan-sensitive), fp32 out
  gemm_t<128, true, false><<<dim3(DI / 128, M_SZ / 128), 256, 0, stream>>>(
      xh, xl, DM, WhT, WlT, DM, b_in, xi, nullptr, DI, DM);

  // 1b) z = x @ W_in[:, DI:] + b_in[DI:]  -- plain bf16 (gate path), bf16 out
  gemm_t<128, false, true><<<dim3(DI / 128, M_SZ / 128), 256, 0, stream>>>(
      xh, nullptr, DM, WhT + (size_t)DI * DM, nullptr, DM,
      b_in + DI, nullptr, zb, DI, DM);

  // 2) xc = silu(causal_dwconv(xi) + b_conv)
  conv_silu_kernel<<<M_SZ * DI / 256, 256, 0, stream>>>(xi, W_conv, b_conv, xc);

  // 3) Bm, Cm projections (fp32)
  gemm_bc_kernel<<<M_SZ * 32 / 256, 256, 0, stream>>>(xc, W_B, b_B, W_C, b_C, Bm, Cm);

  // 4) selective scan + gating -> yg bf16 (overwrites dead xi region)
  //    16 ch/block = 4 barrier-free waves; DPP reduce; full-line xc reads
  scan_kernel<<<dim3(DI / SCH, B_SZ), 256, 0, stream>>>(xc, zb, Bm, Cm, A_log, Dv, yg);

  // 5) out = yg @ W_out + b_out, pure bf16 MFMA (BN=64)
  gemm_t<64, false, false><<<dim3(DM / 64, M_SZ / 128), 256, 0, stream>>>(
      yg, nullptr, DI, WoT, nullptr, DI, b_out, out, nullptr, DM, DI);
}